// Round 1
// baseline (43.391 us; speedup 1.0000x reference)
//
#include <hip/hip_runtime.h>
#include <math.h>

#define N 4096
#define TILE 256
#define NBLK_1D 16   // N / TILE
#define FEPS 1e-7f

// ---------------------------------------------------------------------------
// ws layout:
//   [0, 128)            : double wd[16]   (wd[0] = focal_mean)
//   [128, 128 + 5*N*4)  : float rowA[N], rowB[N], rowAB[N], rowAA[N], rowBB[N]
// ---------------------------------------------------------------------------

__device__ __forceinline__ double block_reduce(double v) {
    __shared__ double buf[4];
    int tid = threadIdx.x;
    #pragma unroll
    for (int o = 32; o > 0; o >>= 1) v += __shfl_down(v, o, 64);
    __syncthreads();                   // protect buf reuse across calls
    if ((tid & 63) == 0) buf[tid >> 6] = v;
    __syncthreads();
    return buf[0] + buf[1] + buf[2] + buf[3];
}

// ---------------------------------------------------------------------------
// Kernel 1: focal BCE (single block) + zero the row accumulators
// ---------------------------------------------------------------------------
__global__ __launch_bounds__(256) void k_focal(
        const float* __restrict__ target,
        const float* __restrict__ output,
        const float* __restrict__ y_class,
        const float* __restrict__ y_pred_class,
        double* __restrict__ wd,
        float* __restrict__ row_zero /* 5*N floats */) {
    int tid = threadIdx.x;

    // zero accumulators for the dcorr passes (stream-ordered before k_pass1)
    for (int i = tid; i < 5 * N; i += 256) row_zero[i] = 0.0f;

    // stage 1: mean/std of y_pred_class, sum of y_class
    double s_ypc = 0.0, s_ypc2 = 0.0, s_yc = 0.0;
    for (int i = tid; i < N; i += 256) {
        float ypc = y_pred_class[i];
        s_ypc  += (double)ypc;
        s_ypc2 += (double)ypc * (double)ypc;
        s_yc   += (double)y_class[i];
    }
    double t_ypc  = block_reduce(s_ypc);
    double t_ypc2 = block_reduce(s_ypc2);
    double t_yc   = block_reduce(s_yc);

    __shared__ float  sm, sinv2s;
    __shared__ double s_sum1myc;
    if (tid == 0) {
        double m   = t_ypc / (double)N;
        double var = t_ypc2 / (double)N - m * m;
        double sd  = sqrt(var > 0.0 ? var : 0.0);
        sm     = (float)m;
        sinv2s = (float)(1.0 / (2.0 * sd));
        s_sum1myc = (double)N - t_yc;
    }
    __syncthreads();

    // stage 2: class_weight_factor and weighted BCE sums
    float m = sm, inv2s = sinv2s;
    double s_cwf = 0.0, s_cwfb = 0.0;
    for (int i = tid; i < N; i += 256) {
        float yc  = y_class[i];
        float ypc = y_pred_class[i];
        float nrm = (ypc - m) * inv2s + 0.5f;
        nrm = fminf(fmaxf(nrm, 0.0f), 1.0f);
        float c1  = (1.0f - yc) * nrm;
        float cwf = c1 * c1;                       // GAMMA = 2
        float x = fminf(fmaxf(output[i], FEPS), 1.0f - FEPS);
        float t = target[i];
        float bce = -t * logf(x) - (1.0f - t) * logf(1.0f - x);
        s_cwf  += (double)cwf;
        s_cwfb += (double)cwf * (double)bce;
    }
    double t_cwf  = block_reduce(s_cwf);
    double t_cwfb = block_reduce(s_cwfb);
    if (tid == 0) {
        double norm_factor = s_sum1myc / t_cwf;
        wd[0] = t_cwfb * norm_factor / (double)N;  // mean(focal)
    }
}

// ---------------------------------------------------------------------------
// Kernel 2: pass 1 — row sums  rowA[i] = sum_j |v1[i]-v1[j]|*w[j]  (and rowB)
// grid = 256 blocks: (bi, bj) tiles of 256x256 pairs
// ---------------------------------------------------------------------------
__global__ __launch_bounds__(256) void k_pass1(
        const float* __restrict__ v1,
        const float* __restrict__ v2,
        const float* __restrict__ w,
        float* __restrict__ rowA,
        float* __restrict__ rowB) {
    __shared__ float s1[TILE], s2[TILE], sw[TILE];
    int tid = threadIdx.x;
    int bi = blockIdx.x & (NBLK_1D - 1);
    int bj = blockIdx.x >> 4;
    int j0 = bj * TILE;

    s1[tid] = v1[j0 + tid];
    s2[tid] = v2[j0 + tid];
    sw[tid] = w [j0 + tid];
    __syncthreads();

    int i = bi * TILE + tid;
    float a = v1[i];
    float b = v2[i];
    float sa = 0.0f, sb = 0.0f;
    #pragma unroll 16
    for (int j = 0; j < TILE; ++j) {
        sa = fmaf(fabsf(a - s1[j]), sw[j], sa);
        sb = fmaf(fabsf(b - s2[j]), sw[j], sb);
    }
    atomicAdd(&rowA[i], sa);
    atomicAdd(&rowB[i], sb);
}

// ---------------------------------------------------------------------------
// Kernel 3: pass 2 — centered products.
//   Am_ij = |v1i-v1j| - aavg_j - (aavg_i - gA)
//   rowAB[i] += sum_j Am*Bm*w_j ; rowAA += Am*Am*w_j ; rowBB += Bm*Bm*w_j
// Each block first (redundantly) reduces gA,gB from rowA/rowB (L2-hit).
// ---------------------------------------------------------------------------
__global__ __launch_bounds__(256) void k_pass2(
        const float* __restrict__ v1,
        const float* __restrict__ v2,
        const float* __restrict__ w,
        const float* __restrict__ rowA,
        const float* __restrict__ rowB,
        float* __restrict__ rowAB,
        float* __restrict__ rowAA,
        float* __restrict__ rowBB) {
    __shared__ float s1[TILE], s2[TILE], sw[TILE], sav[TILE], sbv[TILE];
    int tid = threadIdx.x;
    int bi = blockIdx.x & (NBLK_1D - 1);
    int bj = blockIdx.x >> 4;
    int j0 = bj * TILE;
    const float invN = 1.0f / (float)N;

    // stage j-tile
    {
        int j = j0 + tid;
        s1[tid]  = v1[j];
        s2[tid]  = v2[j];
        sw[tid]  = w[j];
        sav[tid] = rowA[j] * invN;   // aavg_j
        sbv[tid] = rowB[j] * invN;   // bavg_j
    }
    __syncthreads();

    // grand means gA = sum_i rowA[i]*w[i] / N^2  (redundant per block, L2-hit)
    double sgA = 0.0, sgB = 0.0;
    for (int i = tid; i < N; i += 256) {
        double wi = (double)w[i];
        sgA += (double)rowA[i] * wi;
        sgB += (double)rowB[i] * wi;
    }
    const double NN = (double)N * (double)N;
    float gA = (float)(block_reduce(sgA) / NN);
    float gB = (float)(block_reduce(sgB) / NN);

    int i = bi * TILE + tid;
    float a = v1[i];
    float b = v2[i];
    float cA = rowA[i] * invN - gA;   // aavg_i - gA
    float cB = rowB[i] * invN - gB;

    float ab = 0.0f, aa = 0.0f, bb = 0.0f;
    #pragma unroll 8
    for (int j = 0; j < TILE; ++j) {
        float Am = fabsf(a - s1[j]) - sav[j] - cA;
        float Bm = fabsf(b - s2[j]) - sbv[j] - cB;
        float wj = sw[j];
        float Amw = Am * wj;
        float Bmw = Bm * wj;
        ab = fmaf(Amw, Bm, ab);
        aa = fmaf(Amw, Am, aa);
        bb = fmaf(Bmw, Bm, bb);
    }
    atomicAdd(&rowAB[i], ab);
    atomicAdd(&rowAA[i], aa);
    atomicAdd(&rowBB[i], bb);
}

// ---------------------------------------------------------------------------
// Kernel 4: final reduction + power branch + combine with focal mean
// ---------------------------------------------------------------------------
__global__ __launch_bounds__(256) void k_final(
        const float* __restrict__ rowAB,
        const float* __restrict__ rowAA,
        const float* __restrict__ rowBB,
        const float* __restrict__ w,
        const double* __restrict__ wd,
        const int* __restrict__ power,
        float* __restrict__ out) {
    int tid = threadIdx.x;
    double sab = 0.0, saa = 0.0, sbb = 0.0;
    for (int i = tid; i < N; i += 256) {
        double wi = (double)w[i];
        sab += fabs((double)rowAB[i]) * wi;   // ABavg = |row mean| before w_i
        saa += (double)rowAA[i] * wi;
        sbb += (double)rowBB[i] * wi;
    }
    double tab = block_reduce(sab);
    double taa = block_reduce(saa);
    double tbb = block_reduce(sbb);
    if (tid == 0) {
        const double NN = (double)N * (double)N;
        double mAB = tab / NN;
        double mAA = taa / NN;
        double mBB = tbb / NN;
        int p = power[0];
        double d;
        if (p == 1) {
            d = mAB / sqrt(fabs(mAA * mBB) + 1e-12);
        } else if (p == 2) {
            d = (mAB * mAB) / (fabs(mAA * mBB) + 1e-12);
        } else {
            d = pow(mAB / sqrt(mAA * mBB) + 1e-12, (double)p);
        }
        if (isnan(d)) d = 0.0;
        if (d < 0.0)  d = 0.0;
        out[0] = (float)(wd[0] + 1000.0 * d);
    }
}

// ---------------------------------------------------------------------------
extern "C" void kernel_launch(void* const* d_in, const int* in_sizes, int n_in,
                              void* d_out, int out_size, void* d_ws, size_t ws_size,
                              hipStream_t stream) {
    const float* target       = (const float*)d_in[0];
    const float* output       = (const float*)d_in[1];
    const float* y_class      = (const float*)d_in[2];
    const float* y_pred_class = (const float*)d_in[3];
    const float* var_1        = (const float*)d_in[4];
    const float* var_2        = (const float*)d_in[5];
    const float* normedweight = (const float*)d_in[6];
    const int*   power        = (const int*)d_in[7];
    float* out = (float*)d_out;

    char*   ws    = (char*)d_ws;
    double* wd    = (double*)ws;
    float*  rowA  = (float*)(ws + 128);
    float*  rowB  = rowA  + N;
    float*  rowAB = rowB  + N;
    float*  rowAA = rowAB + N;
    float*  rowBB = rowAA + N;

    k_focal<<<1, 256, 0, stream>>>(target, output, y_class, y_pred_class, wd, rowA);
    k_pass1<<<NBLK_1D * NBLK_1D, 256, 0, stream>>>(var_1, var_2, normedweight, rowA, rowB);
    k_pass2<<<NBLK_1D * NBLK_1D, 256, 0, stream>>>(var_1, var_2, normedweight,
                                                   rowA, rowB, rowAB, rowAA, rowBB);
    k_final<<<1, 256, 0, stream>>>(rowAB, rowAA, rowBB, normedweight, wd, power, out);
}

// Round 2
// 37.025 us; speedup vs baseline: 1.1719x; 1.1719x over previous
//
#include <hip/hip_runtime.h>
#include <math.h>

#define N 4096
#define RPB 16          // rows per block
#define LANES 16        // j-lanes per row
#define NBLK (N / RPB)  // 256 pass blocks
#define HALF 2048       // K2 j-tile half size
#define FEPS 1e-7f

// ---------------------------------------------------------------------------
// ws layout (bytes):
//   [0,8)        double wd_focal
//   [16,20)      int    counter
//   [64,  2112)  double pAB[256]
//   [2112,4160)  double pAA[256]
//   [4160,6208)  double pBB[256]
//   [6208, +16K) float  rowA[N]
//   [.. , +16K)  float  rowB[N]
// ---------------------------------------------------------------------------

__device__ __forceinline__ double block_reduce(double v) {
    __shared__ double buf[4];
    int tid = threadIdx.x;
    #pragma unroll
    for (int o = 32; o > 0; o >>= 1) v += __shfl_down(v, o, 64);
    __syncthreads();
    if ((tid & 63) == 0) buf[tid >> 6] = v;
    __syncthreads();
    return buf[0] + buf[1] + buf[2] + buf[3];
}

// ---------------------------------------------------------------------------
// K1: blocks 0..255 -> pass-1 row sums (no atomics); block 256 -> focal BCE
// ---------------------------------------------------------------------------
__global__ __launch_bounds__(256) void k1(
        const float* __restrict__ target,
        const float* __restrict__ output,
        const float* __restrict__ y_class,
        const float* __restrict__ y_pred_class,
        const float* __restrict__ v1,
        const float* __restrict__ v2,
        const float* __restrict__ w,
        double* __restrict__ wd,
        int* __restrict__ counter,
        float* __restrict__ rowA,
        float* __restrict__ rowB) {
    int tid = threadIdx.x;
    int b = blockIdx.x;

    if (b == NBLK) {
        // ------------------ focal BCE block ------------------
        if (tid == 0) *counter = 0;
        double s_ypc = 0.0, s_ypc2 = 0.0, s_yc = 0.0;
        for (int i = tid; i < N; i += 256) {
            float ypc = y_pred_class[i];
            s_ypc  += (double)ypc;
            s_ypc2 += (double)ypc * (double)ypc;
            s_yc   += (double)y_class[i];
        }
        double t_ypc  = block_reduce(s_ypc);
        double t_ypc2 = block_reduce(s_ypc2);
        double t_yc   = block_reduce(s_yc);

        __shared__ float  sm, sinv2s;
        __shared__ double s_sum1myc;
        if (tid == 0) {
            double m   = t_ypc / (double)N;
            double var = t_ypc2 / (double)N - m * m;
            double sd  = sqrt(var > 0.0 ? var : 0.0);
            sm     = (float)m;
            sinv2s = (float)(1.0 / (2.0 * sd));
            s_sum1myc = (double)N - t_yc;
        }
        __syncthreads();

        float m = sm, inv2s = sinv2s;
        double s_cwf = 0.0, s_cwfb = 0.0;
        for (int i = tid; i < N; i += 256) {
            float yc  = y_class[i];
            float ypc = y_pred_class[i];
            float nrm = (ypc - m) * inv2s + 0.5f;
            nrm = fminf(fmaxf(nrm, 0.0f), 1.0f);
            float c1  = (1.0f - yc) * nrm;
            float cwf = c1 * c1;                    // GAMMA = 2
            float x = fminf(fmaxf(output[i], FEPS), 1.0f - FEPS);
            float t = target[i];
            float bce = -t * logf(x) - (1.0f - t) * logf(1.0f - x);
            s_cwf  += (double)cwf;
            s_cwfb += (double)cwf * (double)bce;
        }
        double t_cwf  = block_reduce(s_cwf);
        double t_cwfb = block_reduce(s_cwfb);
        if (tid == 0) wd[0] = t_cwfb * (s_sum1myc / t_cwf) / (double)N;
        return;
    }

    // ------------------ pass-1 blocks ------------------
    __shared__ float s1[N], s2[N], sw[N];   // 48 KiB
    #pragma unroll
    for (int i = tid * 4; i < N; i += 1024) {
        *(float4*)&s1[i] = *(const float4*)&v1[i];
        *(float4*)&s2[i] = *(const float4*)&v2[i];
        *(float4*)&sw[i] = *(const float4*)&w [i];
    }
    __syncthreads();

    int lane16 = tid & (LANES - 1);
    int r      = tid >> 4;
    int i      = b * RPB + r;
    float a  = s1[i];
    float bb = s2[i];
    float sa = 0.0f, sb = 0.0f;
    #pragma unroll 8
    for (int k = 0; k < N / (LANES * 4); ++k) {      // 64 steps of float4
        int j = 4 * lane16 + 64 * k;
        float4 x1 = *(const float4*)&s1[j];
        float4 x2 = *(const float4*)&s2[j];
        float4 xw = *(const float4*)&sw[j];
        sa = fmaf(fabsf(a - x1.x), xw.x, sa);
        sa = fmaf(fabsf(a - x1.y), xw.y, sa);
        sa = fmaf(fabsf(a - x1.z), xw.z, sa);
        sa = fmaf(fabsf(a - x1.w), xw.w, sa);
        sb = fmaf(fabsf(bb - x2.x), xw.x, sb);
        sb = fmaf(fabsf(bb - x2.y), xw.y, sb);
        sb = fmaf(fabsf(bb - x2.z), xw.z, sb);
        sb = fmaf(fabsf(bb - x2.w), xw.w, sb);
    }
    #pragma unroll
    for (int o = 1; o < LANES; o <<= 1) {
        sa += __shfl_xor(sa, o, LANES);
        sb += __shfl_xor(sb, o, LANES);
    }
    if (lane16 == 0) { rowA[i] = sa; rowB[i] = sb; }
}

// ---------------------------------------------------------------------------
// K2: pass-2 centered products + last-block final reduction
// ---------------------------------------------------------------------------
__global__ __launch_bounds__(256) void k2(
        const float* __restrict__ v1,
        const float* __restrict__ v2,
        const float* __restrict__ w,
        const float* __restrict__ rowA,
        const float* __restrict__ rowB,
        const double* __restrict__ wd,
        const int* __restrict__ power,
        int* __restrict__ counter,
        double* __restrict__ pAB,
        double* __restrict__ pAA,
        double* __restrict__ pBB,
        float* __restrict__ out) {
    __shared__ float s1[HALF], s2[HALF], sw[HALF], sav[HALF], sbv[HALF]; // 40 KiB
    __shared__ double rAB[RPB], rAA[RPB], rBB[RPB];
    int tid = threadIdx.x;
    int b = blockIdx.x;
    const float invN = 1.0f / (float)N;

    // grand means gA,gB (redundant per block; rowA/rowB are L2-hit)
    double sgA = 0.0, sgB = 0.0;
    for (int i = tid; i < N; i += 256) {
        double wi = (double)w[i];
        sgA += (double)rowA[i] * wi;
        sgB += (double)rowB[i] * wi;
    }
    const double NN = (double)N * (double)N;
    float gA = (float)(block_reduce(sgA) / NN);
    float gB = (float)(block_reduce(sgB) / NN);

    int lane16 = tid & (LANES - 1);
    int r      = tid >> 4;
    int i      = b * RPB + r;
    float a  = v1[i];
    float bb = v2[i];
    float cA = rowA[i] * invN - gA;
    float cB = rowB[i] * invN - gB;

    float ab = 0.0f, aa = 0.0f, bbs = 0.0f;
    for (int h = 0; h < 2; ++h) {
        int j0 = h * HALF;
        __syncthreads();
        #pragma unroll
        for (int t = tid * 4; t < HALF; t += 1024) {
            *(float4*)&s1[t] = *(const float4*)&v1[j0 + t];
            *(float4*)&s2[t] = *(const float4*)&v2[j0 + t];
            *(float4*)&sw[t] = *(const float4*)&w [j0 + t];
            float4 ra = *(const float4*)&rowA[j0 + t];
            float4 rb = *(const float4*)&rowB[j0 + t];
            ra.x *= invN; ra.y *= invN; ra.z *= invN; ra.w *= invN;
            rb.x *= invN; rb.y *= invN; rb.z *= invN; rb.w *= invN;
            *(float4*)&sav[t] = ra;
            *(float4*)&sbv[t] = rb;
        }
        __syncthreads();
        #pragma unroll 4
        for (int k = 0; k < HALF / (LANES * 4); ++k) {   // 32 steps of float4
            int j = 4 * lane16 + 64 * k;
            float4 x1 = *(const float4*)&s1[j];
            float4 x2 = *(const float4*)&s2[j];
            float4 xw = *(const float4*)&sw[j];
            float4 xa = *(const float4*)&sav[j];
            float4 xb = *(const float4*)&sbv[j];
            #define STEP(c)                                              \
            {                                                            \
                float Am = fabsf(a  - x1.c) - xa.c - cA;                 \
                float Bm = fabsf(bb - x2.c) - xb.c - cB;                 \
                float Amw = Am * xw.c;                                   \
                ab  = fmaf(Amw, Bm, ab);                                 \
                aa  = fmaf(Amw, Am, aa);                                 \
                bbs = fmaf(Bm * xw.c, Bm, bbs);                          \
            }
            STEP(x) STEP(y) STEP(z) STEP(w)
            #undef STEP
        }
    }
    #pragma unroll
    for (int o = 1; o < LANES; o <<= 1) {
        ab  += __shfl_xor(ab,  o, LANES);
        aa  += __shfl_xor(aa,  o, LANES);
        bbs += __shfl_xor(bbs, o, LANES);
    }
    if (lane16 == 0) {
        double wi = (double)w[i];
        rAB[r] = fabs((double)ab) * wi;    // |row mean * N| weighted
        rAA[r] = (double)aa * wi;
        rBB[r] = (double)bbs * wi;
    }
    __syncthreads();
    if (tid == 0) {
        double tab = 0.0, taa = 0.0, tbb = 0.0;
        #pragma unroll
        for (int q = 0; q < RPB; ++q) { tab += rAB[q]; taa += rAA[q]; tbb += rBB[q]; }
        pAB[b] = tab; pAA[b] = taa; pBB[b] = tbb;
    }

    // ---- last-block-done final reduction ----
    __shared__ int isLast;
    if (tid == 0) {
        __threadfence();
        int old = atomicAdd(counter, 1);
        isLast = (old == NBLK - 1);
    }
    __syncthreads();
    if (!isLast) return;
    __threadfence();

    double vab = pAB[tid], vaa = pAA[tid], vbb = pBB[tid]; // 256 partials, 1/thread
    double tab = block_reduce(vab);
    double taa = block_reduce(vaa);
    double tbb = block_reduce(vbb);
    if (tid == 0) {
        const double NN2 = (double)N * (double)N;
        double mAB = tab / NN2;
        double mAA = taa / NN2;
        double mBB = tbb / NN2;
        int p = power[0];
        double d;
        if (p == 1) {
            d = mAB / sqrt(fabs(mAA * mBB) + 1e-12);
        } else if (p == 2) {
            d = (mAB * mAB) / (fabs(mAA * mBB) + 1e-12);
        } else {
            d = pow(mAB / sqrt(mAA * mBB) + 1e-12, (double)p);
        }
        if (isnan(d)) d = 0.0;
        if (d < 0.0)  d = 0.0;
        out[0] = (float)(wd[0] + 1000.0 * d);
    }
}

// ---------------------------------------------------------------------------
extern "C" void kernel_launch(void* const* d_in, const int* in_sizes, int n_in,
                              void* d_out, int out_size, void* d_ws, size_t ws_size,
                              hipStream_t stream) {
    const float* target       = (const float*)d_in[0];
    const float* output       = (const float*)d_in[1];
    const float* y_class      = (const float*)d_in[2];
    const float* y_pred_class = (const float*)d_in[3];
    const float* var_1        = (const float*)d_in[4];
    const float* var_2        = (const float*)d_in[5];
    const float* normedweight = (const float*)d_in[6];
    const int*   power        = (const int*)d_in[7];
    float* out = (float*)d_out;

    char*   ws      = (char*)d_ws;
    double* wd      = (double*)ws;
    int*    counter = (int*)(ws + 16);
    double* pAB     = (double*)(ws + 64);
    double* pAA     = pAB + NBLK;
    double* pBB     = pAA + NBLK;
    float*  rowA    = (float*)(pBB + NBLK);
    float*  rowB    = rowA + N;

    k1<<<NBLK + 1, 256, 0, stream>>>(target, output, y_class, y_pred_class,
                                     var_1, var_2, normedweight, wd, counter, rowA, rowB);
    k2<<<NBLK, 256, 0, stream>>>(var_1, var_2, normedweight, rowA, rowB,
                                 wd, power, counter, pAB, pAA, pBB, out);
}